// Round 7
// baseline (220.306 us; speedup 1.0000x reference)
//
#include <hip/hip_runtime.h>

// Two-kernel peak detection + ordered compaction, (8,16,512,512) fp32.
// History: R2 single-pass decoupled lookback = 2.9ms (cross-XCD coherence —
// dead end). R4 chunked = 220us. R6 row-per-wave strips (1.25x loads, no
// barriers) = 220us — NEUTRAL => pass1 at a shared floor; residual is
// dispatch overhead + harness floor (~120us). R7: drop the scan kernel;
// pass3 blocks redundantly compute their base offset from the counts array
// (4KB L2-warm read + masked block reduce). 2 dispatches total.

namespace {
constexpr int kB = 8;
constexpr int kC = 16;
constexpr int kH = 512;
constexpr int kW = 512;
constexpr int kNPB = kC * kH * kW;              // 4,194,304 px / batch
constexpr int kMaxPeaks = 262144;
constexpr int kRows = 8;                        // rows per strip
constexpr int kStripsPerBatch = kC * (kH / kRows);   // 1024
constexpr int kNStrips = kB * kStripsPerBatch;  // 8192
constexpr int kWPB = 4;                         // waves (strips) per block
constexpr int kTPB = 64 * kWPB;                 // 256
constexpr long long kPeaksElems = (long long)kB * kMaxPeaks * 3;
constexpr float kNeg = -3.402823466e38f;
}

__device__ __forceinline__ float fmax3(float a, float b, float c) {
  return fmaxf(fmaxf(a, b), c);  // -> v_max3_f32
}

// Pass 1: wave = one 8-row strip of one channel image; lane l owns x=l*8..+7.
// Emits 64 x u64 ballot-mask words per strip (word r*8+j: bit l = flag of px
// (row y0+r, x=l*8+j)) + strip peak count.
__global__ void __launch_bounds__(kTPB)
peak_count_kernel(const float* __restrict__ hm,
                  unsigned long long* __restrict__ bmw,
                  int* __restrict__ cnts) {
  const int t = threadIdx.x, lane = t & 63, wv = t >> 6;
  const int s = blockIdx.x * kWPB + wv;
  const int b = s >> 10;                 // 1024 strips / batch
  const int si = s & 1023;
  const int c = si >> 6;                 // 64 strips / image
  const int y0 = (si & 63) * kRows;
  const float* rp = hm + (long long)b * kNPB + c * (kH * kW) + y0 * kW + lane * 8;

  // Load rows y0-1 .. y0+8 (10 rows x 8 px) up front. Image-edge rows -> -inf.
  float a[10][8];
#pragma unroll
  for (int i = 1; i <= 8; ++i) {
    const float4 q0 = *reinterpret_cast<const float4*>(rp + (i - 1) * kW);
    const float4 q1 = *reinterpret_cast<const float4*>(rp + (i - 1) * kW + 4);
    a[i][0] = q0.x; a[i][1] = q0.y; a[i][2] = q0.z; a[i][3] = q0.w;
    a[i][4] = q1.x; a[i][5] = q1.y; a[i][6] = q1.z; a[i][7] = q1.w;
  }
  if (y0 > 0) {
    const float4 q0 = *reinterpret_cast<const float4*>(rp - kW);
    const float4 q1 = *reinterpret_cast<const float4*>(rp - kW + 4);
    a[0][0] = q0.x; a[0][1] = q0.y; a[0][2] = q0.z; a[0][3] = q0.w;
    a[0][4] = q1.x; a[0][5] = q1.y; a[0][6] = q1.z; a[0][7] = q1.w;
  } else {
#pragma unroll
    for (int j = 0; j < 8; ++j) a[0][j] = kNeg;
  }
  if (y0 + kRows < kH) {
    const float4 q0 = *reinterpret_cast<const float4*>(rp + 8 * kW);
    const float4 q1 = *reinterpret_cast<const float4*>(rp + 8 * kW + 4);
    a[9][0] = q0.x; a[9][1] = q0.y; a[9][2] = q0.z; a[9][3] = q0.w;
    a[9][4] = q1.x; a[9][5] = q1.y; a[9][6] = q1.z; a[9][7] = q1.w;
  } else {
#pragma unroll
    for (int j = 0; j < 8; ++j) a[9][j] = kNeg;
  }

  unsigned long long myword = 0;  // lane (r*8+j) keeps ballot word (r,j)
  int scnt = 0;                   // wave-uniform strip count
#pragma unroll
  for (int r = 0; r < kRows; ++r) {
    float cm[8];
#pragma unroll
    for (int j = 0; j < 8; ++j) cm[j] = fmax3(a[r][j], a[r + 1][j], a[r + 2][j]);
    float hl = __shfl_up(cm[7], 1, 64);
    float hr = __shfl_down(cm[0], 1, 64);
    if (lane == 0) hl = kNeg;    // x = -1 (image edge)
    if (lane == 63) hr = kNeg;   // x = 512 (image edge)
    float m[8];
    m[0] = fmax3(hl, cm[0], cm[1]);
#pragma unroll
    for (int j = 1; j < 7; ++j) m[j] = fmax3(cm[j - 1], cm[j], cm[j + 1]);
    m[7] = fmax3(cm[6], cm[7], hr);
#pragma unroll
    for (int j = 0; j < 8; ++j) {
      const float v = a[r + 1][j];
      const unsigned long long wj = __ballot((v == m[j]) && (v > 0.0f));
      scnt += (int)__popcll(wj);
      if (lane == r * 8 + j) myword = wj;  // wave-uniform value, 1-lane capture
    }
  }
  bmw[(long long)s * 64 + lane] = myword;
  if (lane == 0) cnts[s] = scnt;
}

// Pass 2+3 fused: each block owns 4 consecutive strips of one batch.
// Base offset computed redundantly per block: masked reduce over the batch's
// 1024 counts (4 KB, L2-warm). Then the R6 pass3 body per wave.
__global__ void __launch_bounds__(kTPB)
peak_write_kernel(const float* __restrict__ hm,
                  const unsigned long long* __restrict__ bmw,
                  const int* __restrict__ cnts,
                  float* __restrict__ out) {
  __shared__ int s_pre[kWPB], s_tot[kWPB], s_c[kWPB];
  __shared__ unsigned long long s_w[kWPB][64];
  const int t = threadIdx.x, lane = t & 63, wv = t >> 6;
  const int g = blockIdx.x;
  const int b = g >> 8;                  // 256 groups / batch
  const int g0 = (g & 255) * kWPB;       // first strip (within batch) of block
  const int* cb = cnts + b * kStripsPerBatch;

  // thread t owns counts[t*4 .. t*4+3]; g0 % 4 == 0 -> mask is thread-uniform
  const int4 c4 = *reinterpret_cast<const int4*>(cb + t * 4);
  const int idx0 = t * 4;
  int tot = c4.x + c4.y + c4.z + c4.w;
  int pre = (idx0 < g0) ? tot : 0;
  if (idx0 == g0) { s_c[0] = c4.x; s_c[1] = c4.y; s_c[2] = c4.z; s_c[3] = c4.w; }
#pragma unroll
  for (int d = 32; d >= 1; d >>= 1) {
    pre += __shfl_down(pre, d, 64);
    tot += __shfl_down(tot, d, 64);
  }
  if (lane == 0) { s_pre[wv] = pre; s_tot[wv] = tot; }
  __syncthreads();
  const int base = s_pre[0] + s_pre[1] + s_pre[2] + s_pre[3];
  if (g0 == 0 && t == 0)
    out[kPeaksElems + b] =
        (float)(s_tot[0] + s_tot[1] + s_tot[2] + s_tot[3]);  // counts[b]

  int off0 = base;
  for (int k = 0; k < wv; ++k) off0 += s_c[k];
  if (off0 >= kMaxPeaks) return;  // wave-uniform; no barriers below

  const int s = b * kStripsPerBatch + g0 + wv;
  const int si = g0 + wv, c = si >> 6, y0 = (si & 63) * kRows;
  const float* rp = hm + (long long)b * kNPB + c * (kH * kW) + y0 * kW + lane * 8;

  // conf values (8 rows x 8 px), issued up front
  float4 cv[kRows][2];
#pragma unroll
  for (int r = 0; r < kRows; ++r) {
    cv[r][0] = *reinterpret_cast<const float4*>(rp + r * kW);
    cv[r][1] = *reinterpret_cast<const float4*>(rp + r * kW + 4);
  }

  // mask words -> per-wave LDS region; same-wave produce/consume (lgkmcnt only)
  s_w[wv][lane] = bmw[(long long)s * 64 + lane];

  const unsigned long long pm = (lane == 0) ? 0ull : (~0ull >> (64 - lane));
  int rbase = off0;
  float* pb = out + (long long)b * kMaxPeaks * 3;
#pragma unroll
  for (int r = 0; r < kRows; ++r) {
    unsigned long long w[8];
#pragma unroll
    for (int j = 0; j < 8; ++j) w[j] = s_w[wv][r * 8 + j];
    int lexcl = 0, rowcnt = 0;
#pragma unroll
    for (int j = 0; j < 8; ++j) {
      lexcl += (int)__popcll(w[j] & pm);
      rowcnt += (int)__popcll(w[j]);
    }
    int rank = rbase + lexcl;
    const float vv[8] = {cv[r][0].x, cv[r][0].y, cv[r][0].z, cv[r][0].w,
                         cv[r][1].x, cv[r][1].y, cv[r][1].z, cv[r][1].w};
    const float fy = (float)(y0 + r);
#pragma unroll
    for (int j = 0; j < 8; ++j) {
      const int f = (int)((w[j] >> lane) & 1);
      if (f && rank < kMaxPeaks) {
        float* o = pb + (long long)rank * 3;
        o[0] = (float)(lane * 8 + j);
        o[1] = fy;
        o[2] = vv[j];
      }
      rank += f;
    }
    rbase += rowcnt;
    if (rbase >= kMaxPeaks) break;  // uniform: all later rows past the cap
  }
}

extern "C" void kernel_launch(void* const* d_in, const int* in_sizes, int n_in,
                              void* d_out, int out_size, void* d_ws, size_t ws_size,
                              hipStream_t stream) {
  const float* hm = (const float*)d_in[0];
  float* out = (float*)d_out;

  // ws: masks 8192*64 u64 (4 MB) | strip counts 8192 int
  unsigned long long* bmw = (unsigned long long*)d_ws;
  int* cnts = (int*)(bmw + (long long)kNStrips * 64);

  peak_count_kernel<<<kNStrips / kWPB, kTPB, 0, stream>>>(hm, bmw, cnts);
  peak_write_kernel<<<kNStrips / kWPB, kTPB, 0, stream>>>(hm, bmw, cnts, out);
}